// Round 1
// baseline (68.110 us; speedup 1.0000x reference)
//
#include <hip/hip_runtime.h>

#define NPTS  2048
#define NROWS (2 * NPTS)        // 4096 rows total
#define CCH   32                // channels
#define VOL_V (64 * 128 * 128)  // 1048576
#define INV_T (1.0f / 0.07f)

// ---------------------------------------------------------------------------
// K1: gather E[r][c] = emb[c*V + ind(r)]  (row-major [NROWS][CCH] in ws)
// ---------------------------------------------------------------------------
__global__ __launch_bounds__(256) void gather_k(
    const float* __restrict__ e0, const float* __restrict__ e1,
    const float* __restrict__ loc0, const float* __restrict__ loc1,
    float* __restrict__ E)
{
    int idx = blockIdx.x * 256 + threadIdx.x;
    if (idx >= NROWS * CCH) return;
    int r = idx >> 5;   // / CCH
    int c = idx & 31;   // % CCH
    const float* loc = (r < NPTS) ? (loc0 + 3 * r) : (loc1 + 3 * (r - NPTS));
    const float* e   = (r < NPTS) ? e0 : e1;
    int ind = (int)loc[0] * 16384 + (int)loc[1] * 128 + (int)loc[2];
    E[idx] = e[(size_t)c * VOL_V + ind];
}

// ---------------------------------------------------------------------------
// K2: partial row sums of exp(sim/T), excluding the diagonal.
// One thread per row; j split into nchunks chunks along gridDim.y.
// ---------------------------------------------------------------------------
__global__ __launch_bounds__(256) void rowsum_k(
    const float* __restrict__ E, float* __restrict__ partial, int jper)
{
    int r = blockIdx.x * 256 + threadIdx.x;   // 0..NROWS-1
    int chunk = blockIdx.y;
    int j0 = chunk * jper;
    int j1 = j0 + jper;

    // query row in registers
    float q[CCH];
    const float4* qe = reinterpret_cast<const float4*>(E + (size_t)r * CCH);
    #pragma unroll
    for (int i = 0; i < 8; ++i) {
        float4 v = qe[i];
        q[4 * i + 0] = v.x; q[4 * i + 1] = v.y;
        q[4 * i + 2] = v.z; q[4 * i + 3] = v.w;
    }

    float acc = 0.0f;
    for (int j = j0; j < j1; ++j) {
        int ju = __builtin_amdgcn_readfirstlane(j);  // wave-uniform address
        const float4* row = reinterpret_cast<const float4*>(E) + (size_t)ju * 8;
        float s0 = 0.f, s1 = 0.f, s2 = 0.f, s3 = 0.f;
        #pragma unroll
        for (int i = 0; i < 8; ++i) {
            float4 v = row[i];
            s0 = fmaf(q[4 * i + 0], v.x, s0);
            s1 = fmaf(q[4 * i + 1], v.y, s1);
            s2 = fmaf(q[4 * i + 2], v.z, s2);
            s3 = fmaf(q[4 * i + 3], v.w, s3);
        }
        float s  = (s0 + s1) + (s2 + s3);
        float ex = __expf(s * INV_T);
        acc += (ju == r) ? 0.0f : ex;   // skip diagonal (== ref's sum - diag)
    }
    partial[(size_t)chunk * NROWS + r] = acc;
}

// ---------------------------------------------------------------------------
// K3: per-row contrib = s_pair/T - log(rowsum); block-reduce; atomicAdd.
// ---------------------------------------------------------------------------
__global__ __launch_bounds__(256) void finalize_k(
    const float* __restrict__ E, const float* __restrict__ partial,
    int nchunks, float* __restrict__ out)
{
    __shared__ float red[256];
    int r = blockIdx.x * 256 + threadIdx.x;

    float rs = 0.0f;
    for (int ch = 0; ch < nchunks; ++ch)
        rs += partial[(size_t)ch * NROWS + r];

    int p = (r < NPTS) ? (r + NPTS) : (r - NPTS);
    float s = 0.0f;
    #pragma unroll
    for (int c = 0; c < CCH; ++c)
        s = fmaf(E[(size_t)r * CCH + c], E[(size_t)p * CCH + c], s);

    float contrib = s * INV_T - logf(rs);

    red[threadIdx.x] = contrib;
    __syncthreads();
    #pragma unroll
    for (int off = 128; off > 0; off >>= 1) {
        if (threadIdx.x < off) red[threadIdx.x] += red[threadIdx.x + off];
        __syncthreads();
    }
    if (threadIdx.x == 0)
        atomicAdd(out, -red[0] / (2.0f * NPTS));
}

// ---------------------------------------------------------------------------
extern "C" void kernel_launch(void* const* d_in, const int* in_sizes, int n_in,
                              void* d_out, int out_size, void* d_ws, size_t ws_size,
                              hipStream_t stream)
{
    const float* e0 = (const float*)d_in[0];
    const float* e1 = (const float*)d_in[1];
    const float* l0 = (const float*)d_in[2];
    const float* l1 = (const float*)d_in[3];
    float* out = (float*)d_out;

    float* E       = (float*)d_ws;                  // NROWS*CCH floats = 512 KB
    float* partial = E + (size_t)NROWS * CCH;       // nchunks*NROWS floats

    // pick chunk count that fits the workspace (powers of two)
    int nchunks = 32;
    while (nchunks > 1 &&
           (size_t)NROWS * CCH * 4 + (size_t)nchunks * NROWS * 4 > ws_size)
        nchunks >>= 1;
    int jper = NROWS / nchunks;

    hipMemsetAsync(d_out, 0, sizeof(float), stream);

    gather_k<<<(NROWS * CCH + 255) / 256, 256, 0, stream>>>(e0, e1, l0, l1, E);

    dim3 g2(NROWS / 256, nchunks);
    rowsum_k<<<g2, 256, 0, stream>>>(E, partial, jper);

    finalize_k<<<NROWS / 256, 256, 0, stream>>>(E, partial, nchunks, out);
}

// Round 3
// 21.388 us; speedup vs baseline: 3.1845x; 3.1845x over previous
//
#include <hip/hip_runtime.h>

#define NPTS   2048
#define NROWS  (2 * NPTS)        // 4096
#define CCH    32
#define VOL_V  (64 * 128 * 128)  // 1048576
#define INV_T  (1.0f / 0.07f)
#define NCHUNK 16                // j-chunks; 256 j-tiles / 16 = 16 tiles per chunk

typedef __attribute__((ext_vector_type(8))) short bf16x8;  // 8 bf16 = 4 VGPRs
typedef __attribute__((ext_vector_type(4))) float f32x4;

// ---------------------------------------------------------------------------
// K1: gather E_bf[r][c] = bf16(emb[c*V + ind(r)]); also zero d_out.
// ---------------------------------------------------------------------------
__global__ __launch_bounds__(256) void gather_k(
    const float* __restrict__ e0, const float* __restrict__ e1,
    const float* __restrict__ loc0, const float* __restrict__ loc1,
    unsigned short* __restrict__ Eb, float* __restrict__ out)
{
    int idx = blockIdx.x * 256 + threadIdx.x;   // 0 .. NROWS*CCH-1
    if (idx == 0) out[0] = 0.0f;                // zeroed before finalize's atomics
    if (idx >= NROWS * CCH) return;
    int r = idx >> 5;
    int c = idx & 31;
    const float* loc = (r < NPTS) ? (loc0 + 3 * r) : (loc1 + 3 * (r - NPTS));
    const float* e   = (r < NPTS) ? e0 : e1;
    int ind = (int)loc[0] * 16384 + (int)loc[1] * 128 + (int)loc[2];
    float v = e[(size_t)c * VOL_V + ind];
    unsigned u = __builtin_bit_cast(unsigned, v);
    u += 0x7fff + ((u >> 16) & 1);              // RNE to bf16
    Eb[idx] = (unsigned short)(u >> 16);
}

// ---------------------------------------------------------------------------
// K2: MFMA row sums. Each wave owns 32 r-rows (2 A-frags) and one j-chunk
// (16 j-tiles of 16). Per tile: 1 coalesced 1KB B load + 2 mfma_16x16x32_bf16
// + 8 exp. acc[q] of the 16x16 tile sits at (row=(lane>>4)*4+q, col=lane&15)
// (symmetric S makes the transposed interpretation equally correct).
// ---------------------------------------------------------------------------
__global__ __launch_bounds__(256) void rowsum_k(
    const unsigned short* __restrict__ Eb, float* __restrict__ partial)
{
    int lane    = threadIdx.x & 63;
    int wave_id = blockIdx.x * 4 + (threadIdx.x >> 6);
    int rstripe = wave_id & (NROWS / 32 - 1);   // 0..127
    int chunk   = wave_id >> 7;                 // 0..NCHUNK-1
    int r0      = rstripe * 32;

    int lrow = lane & 15;          // row/col within 16-tile
    int lgrp = lane >> 4;          // 0..3
    int koff = lgrp * 8;           // k-offset of this lane's 8 bf16

    bf16x8 a0 = *(const bf16x8*)(Eb + (size_t)(r0      + lrow) * CCH + koff);
    bf16x8 a1 = *(const bf16x8*)(Eb + (size_t)(r0 + 16 + lrow) * CCH + koff);

    float racc0[4] = {0.f, 0.f, 0.f, 0.f};
    float racc1[4] = {0.f, 0.f, 0.f, 0.f};
    int rg_base0 = r0      + lgrp * 4;          // global row of acc0[q] - q
    int rg_base1 = r0 + 16 + lgrp * 4;

    const f32x4 zero = {0.f, 0.f, 0.f, 0.f};

    #pragma unroll 4
    for (int t = 0; t < 256 / 16 / NCHUNK * 16; ++t) {   // 16 tiles
        int j0 = (chunk * 16 + t) * 16;
        bf16x8 b = *(const bf16x8*)(Eb + (size_t)(j0 + lrow) * CCH + koff);
        f32x4 c0 = __builtin_amdgcn_mfma_f32_16x16x32_bf16(a0, b, zero, 0, 0, 0);
        f32x4 c1 = __builtin_amdgcn_mfma_f32_16x16x32_bf16(a1, b, zero, 0, 0, 0);
        int jg = j0 + lrow;
        #pragma unroll
        for (int q = 0; q < 4; ++q) {
            float ex0 = __expf(c0[q] * INV_T);
            float ex1 = __expf(c1[q] * INV_T);
            racc0[q] += (jg == rg_base0 + q) ? 0.0f : ex0;
            racc1[q] += (jg == rg_base1 + q) ? 0.0f : ex1;
        }
    }

    // reduce across the 16 lanes of each group (cols of the tile)
    #pragma unroll
    for (int q = 0; q < 4; ++q) {
        #pragma unroll
        for (int m = 1; m < 16; m <<= 1) {
            racc0[q] += __shfl_xor(racc0[q], m);
            racc1[q] += __shfl_xor(racc1[q], m);
        }
    }
    if (lrow == 0) {
        #pragma unroll
        for (int q = 0; q < 4; ++q) {
            partial[(size_t)chunk * NROWS + rg_base0 + q] = racc0[q];
            partial[(size_t)chunk * NROWS + rg_base1 + q] = racc1[q];
        }
    }
}

// ---------------------------------------------------------------------------
// K3: contrib = s_pair/T - log(rowsum); block-reduce; atomicAdd into d_out.
// ---------------------------------------------------------------------------
__global__ __launch_bounds__(256) void finalize_k(
    const unsigned short* __restrict__ Eb, const float* __restrict__ partial,
    float* __restrict__ out)
{
    __shared__ float red[256];
    int r = blockIdx.x * 256 + threadIdx.x;

    float rs = 0.0f;
    #pragma unroll
    for (int ch = 0; ch < NCHUNK; ++ch)
        rs += partial[(size_t)ch * NROWS + r];

    int p = (r < NPTS) ? (r + NPTS) : (r - NPTS);
    float s = 0.0f;
    #pragma unroll
    for (int c = 0; c < CCH; ++c) {
        float a = __builtin_bit_cast(float, (unsigned)Eb[(size_t)r * CCH + c] << 16);
        float b = __builtin_bit_cast(float, (unsigned)Eb[(size_t)p * CCH + c] << 16);
        s = fmaf(a, b, s);
    }

    float contrib = s * INV_T - __logf(rs);

    red[threadIdx.x] = contrib;
    __syncthreads();
    #pragma unroll
    for (int off = 128; off > 0; off >>= 1) {
        if (threadIdx.x < off) red[threadIdx.x] += red[threadIdx.x + off];
        __syncthreads();
    }
    if (threadIdx.x == 0)
        atomicAdd(out, -red[0] / (2.0f * NPTS));
}

// ---------------------------------------------------------------------------
extern "C" void kernel_launch(void* const* d_in, const int* in_sizes, int n_in,
                              void* d_out, int out_size, void* d_ws, size_t ws_size,
                              hipStream_t stream)
{
    const float* e0 = (const float*)d_in[0];
    const float* e1 = (const float*)d_in[1];
    const float* l0 = (const float*)d_in[2];
    const float* l1 = (const float*)d_in[3];
    float* out = (float*)d_out;

    unsigned short* Eb = (unsigned short*)d_ws;                       // 256 KB
    float* partial = (float*)((char*)d_ws + (size_t)NROWS * CCH * 2); // 256 KB

    gather_k<<<(NROWS * CCH + 255) / 256, 256, 0, stream>>>(e0, e1, l0, l1, Eb, out);

    // (NROWS/32) stripes * NCHUNK chunks waves, 4 waves per block
    int nwaves = (NROWS / 32) * NCHUNK;
    rowsum_k<<<nwaves / 4, 256, 0, stream>>>(Eb, partial);

    finalize_k<<<NROWS / 256, 256, 0, stream>>>(Eb, partial, out);
}